// Round 1
// baseline (1928.077 us; speedup 1.0000x reference)
//
#include <hip/hip_runtime.h>
#include <math.h>

#define HEADS 16
#define DHEAD 64
#define DIMM 1024
#define NQKV 3072
#define NB 2
#define SEQ 2048
#define MROWS 4096   // NB*SEQ

// ---------------- K1: RMSNorm (F.normalize * sqrt(dim) * gamma) ----------------
__global__ __launch_bounds__(256) void k_rmsnorm(const float* __restrict__ x,
                                                 const float* __restrict__ gamma,
                                                 float* __restrict__ xn) {
  int row = blockIdx.x;
  int t = threadIdx.x;
  float4 v = reinterpret_cast<const float4*>(x + (size_t)row * DIMM)[t];
  float ss = v.x * v.x + v.y * v.y + v.z * v.z + v.w * v.w;
#pragma unroll
  for (int o = 32; o >= 1; o >>= 1) ss += __shfl_xor(ss, o, 64);
  __shared__ float red[4];
  if ((t & 63) == 0) red[t >> 6] = ss;
  __syncthreads();
  ss = red[0] + red[1] + red[2] + red[3];
  float s = 32.0f / fmaxf(sqrtf(ss), 1e-12f);   // sqrt(1024)=32; eps=1e-12
  float4 g = reinterpret_cast<const float4*>(gamma)[t];
  float4 o4;
  o4.x = v.x * s * g.x;
  o4.y = v.y * s * g.y;
  o4.z = v.z * s * g.z;
  o4.w = v.w * s * g.w;
  reinterpret_cast<float4*>(xn + (size_t)row * DIMM)[t] = o4;
}

// ---------------- K1b: mix & gates projections + sigmoid ----------------
// mg[row][0..15] = sigmoid(xn@w_mix + b_mix), mg[row][16..31] = sigmoid(xn@w_gates + b_gates)
__global__ __launch_bounds__(128) void k_mixgates(const float* __restrict__ xn,
                                                  const float* __restrict__ w_mix,
                                                  const float* __restrict__ b_mix,
                                                  const float* __restrict__ w_gates,
                                                  const float* __restrict__ b_gates,
                                                  float* __restrict__ mg) {
  int row = blockIdx.x;
  int t = threadIdx.x;
  int out = t >> 2;   // 0..31
  int part = t & 3;   // 0..3 (256 K-elems each)
  const float* xr = xn + (size_t)row * DIMM;
  const float* w = (out < HEADS) ? (w_mix + out) : (w_gates + (out - HEADS));
  int k0 = part * 256;
  float acc = 0.f;
#pragma unroll 8
  for (int kk = 0; kk < 256; ++kk) acc += xr[k0 + kk] * w[(size_t)(k0 + kk) * HEADS];
  acc += __shfl_xor(acc, 1, 64);
  acc += __shfl_xor(acc, 2, 64);
  if (part == 0) {
    float bias = (out < HEADS) ? b_mix[out] : b_gates[out - HEADS];
    float val = acc + bias;
    mg[(size_t)row * 32 + out] = 1.f / (1.f + __expf(-val));
  }
}

// ---------------- GEMM: C[M,NCOLS] = A[M,1024] @ B[1024,NCOLS] ----------------
// 128x128 tile, BK=16, 256 threads, 8x8 micro-tile.
// MODE 0: QKV epilogue (scatter to q/k/v [b,h,n,d]; orig_v to d_out; v lerped with mix)
// MODE 1: plain store to outp [M,NCOLS]
template <int NCOLS, int MODE>
__global__ __launch_bounds__(256) void k_gemm(const float* __restrict__ A,
                                              const float* __restrict__ Bm,
                                              float* __restrict__ q_buf,
                                              float* __restrict__ k_buf,
                                              float* __restrict__ v_buf,
                                              float* __restrict__ orig_v,
                                              const float* __restrict__ vr,
                                              const float* __restrict__ mg,
                                              float* __restrict__ outp) {
  __shared__ float As[16][132];  // transposed: As[k][m], pad to 132 (2-way max on writes)
  __shared__ float Bs[16][132];  // Bs[k][n]
  int t = threadIdx.x;
  int ty = t >> 4, tx = t & 15;
  int m0 = blockIdx.y * 128, n0 = blockIdx.x * 128;
  float acc[8][8];
#pragma unroll
  for (int i = 0; i < 8; ++i)
#pragma unroll
    for (int j = 0; j < 8; ++j) acc[i][j] = 0.f;

  int lr = t >> 1;          // 0..127 (A tile row)
  int lk = (t & 1) * 8;     // 0 or 8 (A k-offset)
  int bkr = t >> 4;         // 0..15 (B tile row)
  int bc = tx * 8;          // B col offset
  const float* Arow = A + (size_t)(m0 + lr) * DIMM + lk;
  const float* Brow = Bm + (size_t)bkr * NCOLS + n0 + bc;

  for (int k0 = 0; k0 < DIMM; k0 += 16) {
    float4 a0 = *reinterpret_cast<const float4*>(Arow + k0);
    float4 a1 = *reinterpret_cast<const float4*>(Arow + k0 + 4);
    float4 b0 = *reinterpret_cast<const float4*>(Brow + (size_t)k0 * NCOLS);
    float4 b1 = *reinterpret_cast<const float4*>(Brow + (size_t)k0 * NCOLS + 4);
    __syncthreads();
    As[lk + 0][lr] = a0.x; As[lk + 1][lr] = a0.y; As[lk + 2][lr] = a0.z; As[lk + 3][lr] = a0.w;
    As[lk + 4][lr] = a1.x; As[lk + 5][lr] = a1.y; As[lk + 6][lr] = a1.z; As[lk + 7][lr] = a1.w;
    *reinterpret_cast<float4*>(&Bs[bkr][bc]) = b0;
    *reinterpret_cast<float4*>(&Bs[bkr][bc + 4]) = b1;
    __syncthreads();
#pragma unroll
    for (int kk = 0; kk < 16; ++kk) {
      float4 a04 = *reinterpret_cast<const float4*>(&As[kk][ty * 8]);
      float4 a14 = *reinterpret_cast<const float4*>(&As[kk][ty * 8 + 4]);
      float4 b04 = *reinterpret_cast<const float4*>(&Bs[kk][tx * 8]);
      float4 b14 = *reinterpret_cast<const float4*>(&Bs[kk][tx * 8 + 4]);
      float av[8] = {a04.x, a04.y, a04.z, a04.w, a14.x, a14.y, a14.z, a14.w};
      float bv[8] = {b04.x, b04.y, b04.z, b04.w, b14.x, b14.y, b14.z, b14.w};
#pragma unroll
      for (int i = 0; i < 8; ++i)
#pragma unroll
        for (int j = 0; j < 8; ++j) acc[i][j] = fmaf(av[i], bv[j], acc[i][j]);
    }
  }

  if (MODE == 1) {
#pragma unroll
    for (int i = 0; i < 8; ++i) {
      int row = m0 + ty * 8 + i;
      float4 s0 = make_float4(acc[i][0], acc[i][1], acc[i][2], acc[i][3]);
      float4 s1 = make_float4(acc[i][4], acc[i][5], acc[i][6], acc[i][7]);
      float* dst = outp + (size_t)row * NCOLS + n0 + tx * 8;
      *reinterpret_cast<float4*>(dst) = s0;
      *reinterpret_cast<float4*>(dst + 4) = s1;
    }
  } else {
    int c = n0 + tx * 8;
    int part = c >> 10;   // 0=q,1=k,2=v
    int cc = c & 1023;
    int h = cc >> 6;
    int dd = cc & 63;
#pragma unroll
    for (int i = 0; i < 8; ++i) {
      int row = m0 + ty * 8 + i;
      int b_i = row >> 11, n_i = row & 2047;
      size_t idx = (((size_t)(b_i * HEADS + h) * SEQ) + n_i) * DHEAD + dd;
      float4 s0 = make_float4(acc[i][0], acc[i][1], acc[i][2], acc[i][3]);
      float4 s1 = make_float4(acc[i][4], acc[i][5], acc[i][6], acc[i][7]);
      if (part == 0) {
        *reinterpret_cast<float4*>(q_buf + idx) = s0;
        *reinterpret_cast<float4*>(q_buf + idx + 4) = s1;
      } else if (part == 1) {
        *reinterpret_cast<float4*>(k_buf + idx) = s0;
        *reinterpret_cast<float4*>(k_buf + idx + 4) = s1;
      } else {
        *reinterpret_cast<float4*>(orig_v + idx) = s0;
        *reinterpret_cast<float4*>(orig_v + idx + 4) = s1;
        float mixv = mg[(size_t)row * 32 + h];
        float4 r0 = *reinterpret_cast<const float4*>(vr + idx);
        float4 r1 = *reinterpret_cast<const float4*>(vr + idx + 4);
        s0.x += mixv * (r0.x - s0.x); s0.y += mixv * (r0.y - s0.y);
        s0.z += mixv * (r0.z - s0.z); s0.w += mixv * (r0.w - s0.w);
        s1.x += mixv * (r1.x - s1.x); s1.y += mixv * (r1.y - s1.y);
        s1.z += mixv * (r1.z - s1.z); s1.w += mixv * (r1.w - s1.w);
        *reinterpret_cast<float4*>(v_buf + idx) = s0;
        *reinterpret_cast<float4*>(v_buf + idx + 4) = s1;
      }
    }
  }
}

// ---------------- K3: flash attention + sigmoid gating ----------------
// One block = 64 query rows of one (b,h). 128 threads, 8x4 micro-tile.
// LDS: 4 x 16KB float4 arrays, XOR-swizzled (chunk ^ (row&15) ^ (row>>3)).
__device__ __forceinline__ int swz(int r, int ch) {
  return r * 16 + ((ch ^ (r & 15) ^ (r >> 3)) & 15);
}

__global__ __launch_bounds__(128) void k_attn(const float* __restrict__ qb,
                                              const float* __restrict__ kb,
                                              const float* __restrict__ vb,
                                              const float* __restrict__ mg,
                                              float* __restrict__ attn_out) {
  __shared__ float4 Qs[1024];
  __shared__ float4 Ks[1024];
  __shared__ float4 Vs[1024];
  __shared__ float4 Ps[1024];
  int t = threadIdx.x;
  int bh = blockIdx.y;          // 0..31  (b*16+h)
  int q0 = blockIdx.x * 64;
  size_t base = (size_t)bh * SEQ * DHEAD;

  int slr = t >> 1;             // 0..63 staging row
  int sq8 = (t & 1) * 8;        // staging chunk base
  {
    const float4* src = reinterpret_cast<const float4*>(qb + base + (size_t)q0 * DHEAD);
#pragma unroll
    for (int s = 0; s < 8; ++s) Qs[swz(slr, sq8 + s)] = src[slr * 16 + sq8 + s];
  }

  int tr = t >> 4;  // 0..7  -> rows tr*8..+7
  int tc = t & 15;  // 0..15 -> cols tc*4..+3
  float m_i[8], l_i[8], acc[8][4];
#pragma unroll
  for (int i = 0; i < 8; ++i) {
    m_i[i] = -3.0e38f;
    l_i[i] = 0.f;
#pragma unroll
    for (int j = 0; j < 4; ++j) acc[i][j] = 0.f;
  }
  const float4* kp = reinterpret_cast<const float4*>(kb + base);
  const float4* vp = reinterpret_cast<const float4*>(vb + base);

  for (int kt = 0; kt < SEQ / 64; ++kt) {
    float4 krg[8], vrg[8];
    const float4* ksrc = kp + (size_t)(kt * 64) * 16;
    const float4* vsrc = vp + (size_t)(kt * 64) * 16;
#pragma unroll
    for (int s = 0; s < 8; ++s) {
      krg[s] = ksrc[slr * 16 + sq8 + s];
      vrg[s] = vsrc[slr * 16 + sq8 + s];
    }
    __syncthreads();  // previous tile's compute done before overwrite
#pragma unroll
    for (int s = 0; s < 8; ++s) {
      Ks[swz(slr, sq8 + s)] = krg[s];
      Vs[swz(slr, sq8 + s)] = vrg[s];
    }
    __syncthreads();  // K/V tile visible to all waves

    // S = Q K^T (per-thread 8x4 of the 64x64 score tile)
    float sv[8][4];
#pragma unroll
    for (int i = 0; i < 8; ++i)
#pragma unroll
      for (int j = 0; j < 4; ++j) sv[i][j] = 0.f;
#pragma unroll
    for (int ck = 0; ck < 16; ++ck) {
      float4 qv[8], kv[4];
#pragma unroll
      for (int i = 0; i < 8; ++i) qv[i] = Qs[swz(tr * 8 + i, ck)];
#pragma unroll
      for (int j = 0; j < 4; ++j) kv[j] = Ks[swz(tc * 4 + j, ck)];
#pragma unroll
      for (int i = 0; i < 8; ++i)
#pragma unroll
        for (int j = 0; j < 4; ++j) {
          sv[i][j] = fmaf(qv[i].x, kv[j].x, sv[i][j]);
          sv[i][j] = fmaf(qv[i].y, kv[j].y, sv[i][j]);
          sv[i][j] = fmaf(qv[i].z, kv[j].z, sv[i][j]);
          sv[i][j] = fmaf(qv[i].w, kv[j].w, sv[i][j]);
        }
    }

    // online softmax per query row (row group = 16 consecutive lanes)
#pragma unroll
    for (int i = 0; i < 8; ++i) {
      float s0 = sv[i][0] * 0.125f, s1 = sv[i][1] * 0.125f;
      float s2 = sv[i][2] * 0.125f, s3 = sv[i][3] * 0.125f;
      float rm = fmaxf(fmaxf(s0, s1), fmaxf(s2, s3));
      rm = fmaxf(rm, __shfl_xor(rm, 1, 64));
      rm = fmaxf(rm, __shfl_xor(rm, 2, 64));
      rm = fmaxf(rm, __shfl_xor(rm, 4, 64));
      rm = fmaxf(rm, __shfl_xor(rm, 8, 64));
      float mnew = fmaxf(m_i[i], rm);
      float corr = __expf(m_i[i] - mnew);
      float p0 = __expf(s0 - mnew), p1 = __expf(s1 - mnew);
      float p2 = __expf(s2 - mnew), p3 = __expf(s3 - mnew);
      float rs = p0 + p1 + p2 + p3;
      rs += __shfl_xor(rs, 1, 64);
      rs += __shfl_xor(rs, 2, 64);
      rs += __shfl_xor(rs, 4, 64);
      rs += __shfl_xor(rs, 8, 64);
      l_i[i] = l_i[i] * corr + rs;
      m_i[i] = mnew;
      acc[i][0] *= corr; acc[i][1] *= corr; acc[i][2] *= corr; acc[i][3] *= corr;
      Ps[swz(tr * 8 + i, tc)] = make_float4(p0, p1, p2, p3);
    }
    // Ps rows are wave-private (wave w owns rows 32w..32w+31): no block sync needed.

    // acc += P @ V
#pragma unroll
    for (int ck = 0; ck < 16; ++ck) {
      float4 pv[8], vv[4];
#pragma unroll
      for (int i = 0; i < 8; ++i) pv[i] = Ps[swz(tr * 8 + i, ck)];
#pragma unroll
      for (int kkp = 0; kkp < 4; ++kkp) vv[kkp] = Vs[swz(ck * 4 + kkp, tc)];
#pragma unroll
      for (int i = 0; i < 8; ++i) {
        float pc[4] = {pv[i].x, pv[i].y, pv[i].z, pv[i].w};
#pragma unroll
        for (int kkp = 0; kkp < 4; ++kkp) {
          acc[i][0] = fmaf(pc[kkp], vv[kkp].x, acc[i][0]);
          acc[i][1] = fmaf(pc[kkp], vv[kkp].y, acc[i][1]);
          acc[i][2] = fmaf(pc[kkp], vv[kkp].z, acc[i][2]);
          acc[i][3] = fmaf(pc[kkp], vv[kkp].w, acc[i][3]);
        }
      }
    }
  }

  // finalize: /l, * sigmoid gate, store [b, n, h*64+d]
  int b_i = bh >> 4, h = bh & 15;
#pragma unroll
  for (int i = 0; i < 8; ++i) {
    int n_i = q0 + tr * 8 + i;
    int rowg = b_i * SEQ + n_i;
    float gate = mg[(size_t)rowg * 32 + HEADS + h];
    float f = gate / l_i[i];
    float4 o = make_float4(acc[i][0] * f, acc[i][1] * f, acc[i][2] * f, acc[i][3] * f);
    *reinterpret_cast<float4*>(attn_out + (size_t)rowg * (HEADS * DHEAD) + h * DHEAD + tc * 4) = o;
  }
}

// ---------------- launch ----------------
extern "C" void kernel_launch(void* const* d_in, const int* in_sizes, int n_in,
                              void* d_out, int out_size, void* d_ws, size_t ws_size,
                              hipStream_t stream) {
  const float* x       = (const float*)d_in[0];
  const float* vr      = (const float*)d_in[1];
  const float* gamma   = (const float*)d_in[2];
  const float* w_qkv   = (const float*)d_in[3];
  const float* w_mix   = (const float*)d_in[4];
  const float* b_mix   = (const float*)d_in[5];
  const float* w_gates = (const float*)d_in[6];
  const float* b_gates = (const float*)d_in[7];
  const float* w_out   = (const float*)d_in[8];

  float* out = (float*)d_out;
  float* orig_v = out + (size_t)MROWS * DIMM;  // second tuple output [b,h,n,d]

  float* ws = (float*)d_ws;
  const size_t BUF = (size_t)MROWS * DIMM;     // 4,194,304 floats
  float* xn       = ws;                        // [4096,1024]; reused as attn_out after QKV
  float* q_buf    = ws + BUF;                  // [b,h,n,d]
  float* k_buf    = ws + 2 * BUF;
  float* v_buf    = ws + 3 * BUF;
  float* mg       = ws + 4 * BUF;              // [4096][32]: mix | gates
  float* attn_out = xn;                        // alias: xn dead after QKV GEMM

  k_rmsnorm<<<dim3(MROWS), dim3(256), 0, stream>>>(x, gamma, xn);
  k_mixgates<<<dim3(MROWS), dim3(128), 0, stream>>>(xn, w_mix, b_mix, w_gates, b_gates, mg);
  k_gemm<NQKV, 0><<<dim3(NQKV / 128, MROWS / 128), dim3(256), 0, stream>>>(
      xn, w_qkv, q_buf, k_buf, v_buf, orig_v, vr, mg, nullptr);
  k_attn<<<dim3(SEQ / 64, NB * HEADS), dim3(128), 0, stream>>>(q_buf, k_buf, v_buf, mg, attn_out);
  k_gemm<DIMM, 1><<<dim3(DIMM / 128, MROWS / 128), dim3(256), 0, stream>>>(
      attn_out, w_out, nullptr, nullptr, nullptr, nullptr, nullptr, nullptr, out);
}

// Round 2
// 708.648 us; speedup vs baseline: 2.7208x; 2.7208x over previous
//
#include <hip/hip_runtime.h>
#include <math.h>

#define HEADS 16
#define DHEAD 64
#define DIMM 1024
#define NQKV 3072
#define NB 2
#define SEQ 2048
#define MROWS 4096   // NB*SEQ

typedef unsigned short ushort_t;
typedef unsigned int uint_t;
typedef __attribute__((ext_vector_type(8))) short short8;
typedef __attribute__((ext_vector_type(8))) unsigned short u16x8;
typedef __attribute__((ext_vector_type(16))) float f32x16;

__device__ __forceinline__ ushort_t f2bf(float f) {
  uint_t u = __float_as_uint(f);
  u += 0x7fffu + ((u >> 16) & 1u);   // RNE
  return (ushort_t)(u >> 16);
}

__device__ __forceinline__ uint_t cvtpk_bf16(float lo, float hi) {
  uint_t r;
  asm("v_cvt_pk_bf16_f32 %0, %1, %2" : "=v"(r) : "v"(lo), "v"(hi));
  return r;
}

__device__ __forceinline__ f32x16 mfma32(short8 a, short8 b, f32x16 c) {
  return __builtin_amdgcn_mfma_f32_32x32x16_bf16(a, b, c, 0, 0, 0);
}

// ---------------- K1: RMSNorm (F.normalize * sqrt(dim) * gamma) ----------------
__global__ __launch_bounds__(256) void k_rmsnorm(const float* __restrict__ x,
                                                 const float* __restrict__ gamma,
                                                 float* __restrict__ xn) {
  int row = blockIdx.x;
  int t = threadIdx.x;
  float4 v = reinterpret_cast<const float4*>(x + (size_t)row * DIMM)[t];
  float ss = v.x * v.x + v.y * v.y + v.z * v.z + v.w * v.w;
#pragma unroll
  for (int o = 32; o >= 1; o >>= 1) ss += __shfl_xor(ss, o, 64);
  __shared__ float red[4];
  if ((t & 63) == 0) red[t >> 6] = ss;
  __syncthreads();
  ss = red[0] + red[1] + red[2] + red[3];
  float s = 32.0f / fmaxf(sqrtf(ss), 1e-12f);
  float4 g = reinterpret_cast<const float4*>(gamma)[t];
  float4 o4;
  o4.x = v.x * s * g.x;
  o4.y = v.y * s * g.y;
  o4.z = v.z * s * g.z;
  o4.w = v.w * s * g.w;
  reinterpret_cast<float4*>(xn + (size_t)row * DIMM)[t] = o4;
}

// ---------------- K1b: mix & gates projections + sigmoid ----------------
__global__ __launch_bounds__(128) void k_mixgates(const float* __restrict__ xn,
                                                  const float* __restrict__ w_mix,
                                                  const float* __restrict__ b_mix,
                                                  const float* __restrict__ w_gates,
                                                  const float* __restrict__ b_gates,
                                                  float* __restrict__ mg) {
  int row = blockIdx.x;
  int t = threadIdx.x;
  int out = t >> 2;   // 0..31
  int part = t & 3;   // 0..3 (256 K-elems each)
  const float* xr = xn + (size_t)row * DIMM;
  const float* w = (out < HEADS) ? (w_mix + out) : (w_gates + (out - HEADS));
  int k0 = part * 256;
  float acc = 0.f;
#pragma unroll 8
  for (int kk = 0; kk < 256; ++kk) acc += xr[k0 + kk] * w[(size_t)(k0 + kk) * HEADS];
  acc += __shfl_xor(acc, 1, 64);
  acc += __shfl_xor(acc, 2, 64);
  if (part == 0) {
    float bias = (out < HEADS) ? b_mix[out] : b_gates[out - HEADS];
    float val = acc + bias;
    mg[(size_t)row * 32 + out] = 1.f / (1.f + __expf(-val));
  }
}

// ---------------- GEMM: C[M,NCOLS] = A[M,1024] @ B[1024,NCOLS] ----------------
// MODE 0: QKV epilogue -> q/k/v as bf16 [b,h,n,d]; orig_v fp32 to d_out; v lerped
// MODE 1: plain fp32 store
template <int NCOLS, int MODE>
__global__ __launch_bounds__(256) void k_gemm(const float* __restrict__ A,
                                              const float* __restrict__ Bm,
                                              ushort_t* __restrict__ q_bf,
                                              ushort_t* __restrict__ k_bf,
                                              ushort_t* __restrict__ v_bf,
                                              float* __restrict__ orig_v,
                                              const float* __restrict__ vr,
                                              const float* __restrict__ mg,
                                              float* __restrict__ outp) {
  __shared__ float As[16][132];
  __shared__ float Bs[16][132];
  int t = threadIdx.x;
  int ty = t >> 4, tx = t & 15;
  int m0 = blockIdx.y * 128, n0 = blockIdx.x * 128;
  float acc[8][8];
#pragma unroll
  for (int i = 0; i < 8; ++i)
#pragma unroll
    for (int j = 0; j < 8; ++j) acc[i][j] = 0.f;

  int lr = t >> 1;
  int lk = (t & 1) * 8;
  int bkr = t >> 4;
  int bc = tx * 8;
  const float* Arow = A + (size_t)(m0 + lr) * DIMM + lk;
  const float* Brow = Bm + (size_t)bkr * NCOLS + n0 + bc;

  for (int k0 = 0; k0 < DIMM; k0 += 16) {
    float4 a0 = *reinterpret_cast<const float4*>(Arow + k0);
    float4 a1 = *reinterpret_cast<const float4*>(Arow + k0 + 4);
    float4 b0 = *reinterpret_cast<const float4*>(Brow + (size_t)k0 * NCOLS);
    float4 b1 = *reinterpret_cast<const float4*>(Brow + (size_t)k0 * NCOLS + 4);
    __syncthreads();
    As[lk + 0][lr] = a0.x; As[lk + 1][lr] = a0.y; As[lk + 2][lr] = a0.z; As[lk + 3][lr] = a0.w;
    As[lk + 4][lr] = a1.x; As[lk + 5][lr] = a1.y; As[lk + 6][lr] = a1.z; As[lk + 7][lr] = a1.w;
    *reinterpret_cast<float4*>(&Bs[bkr][bc]) = b0;
    *reinterpret_cast<float4*>(&Bs[bkr][bc + 4]) = b1;
    __syncthreads();
#pragma unroll
    for (int kk = 0; kk < 16; ++kk) {
      float4 a04 = *reinterpret_cast<const float4*>(&As[kk][ty * 8]);
      float4 a14 = *reinterpret_cast<const float4*>(&As[kk][ty * 8 + 4]);
      float4 b04 = *reinterpret_cast<const float4*>(&Bs[kk][tx * 8]);
      float4 b14 = *reinterpret_cast<const float4*>(&Bs[kk][tx * 8 + 4]);
      float av[8] = {a04.x, a04.y, a04.z, a04.w, a14.x, a14.y, a14.z, a14.w};
      float bv[8] = {b04.x, b04.y, b04.z, b04.w, b14.x, b14.y, b14.z, b14.w};
#pragma unroll
      for (int i = 0; i < 8; ++i)
#pragma unroll
        for (int j = 0; j < 8; ++j) acc[i][j] = fmaf(av[i], bv[j], acc[i][j]);
    }
  }

  if (MODE == 1) {
#pragma unroll
    for (int i = 0; i < 8; ++i) {
      int row = m0 + ty * 8 + i;
      float4 s0 = make_float4(acc[i][0], acc[i][1], acc[i][2], acc[i][3]);
      float4 s1 = make_float4(acc[i][4], acc[i][5], acc[i][6], acc[i][7]);
      float* dst = outp + (size_t)row * NCOLS + n0 + tx * 8;
      *reinterpret_cast<float4*>(dst) = s0;
      *reinterpret_cast<float4*>(dst + 4) = s1;
    }
  } else {
    int c = n0 + tx * 8;
    int part = c >> 10;   // 0=q,1=k,2=v
    int cc = c & 1023;
    int h = cc >> 6;
    int dd = cc & 63;
#pragma unroll
    for (int i = 0; i < 8; ++i) {
      int row = m0 + ty * 8 + i;
      int b_i = row >> 11, n_i = row & 2047;
      size_t idx = (((size_t)(b_i * HEADS + h) * SEQ) + n_i) * DHEAD + dd;
      if (part == 0) {
        u16x8 wv;
#pragma unroll
        for (int j = 0; j < 8; ++j) wv[j] = f2bf(acc[i][j]);
        *reinterpret_cast<u16x8*>(q_bf + idx) = wv;
      } else if (part == 1) {
        u16x8 wv;
#pragma unroll
        for (int j = 0; j < 8; ++j) wv[j] = f2bf(acc[i][j]);
        *reinterpret_cast<u16x8*>(k_bf + idx) = wv;
      } else {
        float4 s0 = make_float4(acc[i][0], acc[i][1], acc[i][2], acc[i][3]);
        float4 s1 = make_float4(acc[i][4], acc[i][5], acc[i][6], acc[i][7]);
        *reinterpret_cast<float4*>(orig_v + idx) = s0;
        *reinterpret_cast<float4*>(orig_v + idx + 4) = s1;
        float mixv = mg[(size_t)row * 32 + h];
        const float* vrp = vr + idx;
        u16x8 wv;
#pragma unroll
        for (int j = 0; j < 8; ++j) {
          float fv = acc[i][j] + mixv * (vrp[j] - acc[i][j]);
          wv[j] = f2bf(fv);
        }
        *reinterpret_cast<u16x8*>(v_bf + idx) = wv;
      }
    }
  }
}

// ---------------- K3: bf16 MFMA flash attention + sigmoid gating ----------------
// 256 threads = 4 waves; block = 128 q-rows of one (b,h); KV tiles of 64.
// Swapped QK^T: S^T[m][n] = mfma(Kfrag, Qfrag) -> lane holds one query col.
// Swapped PV:   O^T[d][n] = mfma(Vt_frag, Pa)  -> lane keeps same query col.
// K_lds / Vt_lds: 64x64 bf16, 128B rows, chunk^(row&7) XOR swizzle (conflict-free b128).
__global__ __launch_bounds__(256, 2) void k_attn(const ushort_t* __restrict__ qb,
                                                 const ushort_t* __restrict__ kb,
                                                 const ushort_t* __restrict__ vb,
                                                 const float* __restrict__ mg,
                                                 float* __restrict__ attn_out) {
  __shared__ uint4 Ksm[64 * 8];     // [row][swz chunk]
  __shared__ uint_t Vtsm[64 * 32];  // [d][...] byte = d*128 + swz_chunk*16 + sub

  const int t = threadIdx.x;
  const int w = t >> 6;       // wave 0..3
  const int l = t & 63;
  const int hi = l >> 5;
  const int ln = l & 31;
  const int bh = blockIdx.y;  // b*16+h
  const int q0 = blockIdx.x * 128;
  const int b_i = bh >> 4, h = bh & 15;

  const size_t base = (size_t)bh * SEQ * DHEAD;  // elements

  // Q fragments in registers: B-operand, col = query = ln, k = d-slice
  short8 qf[4];
  {
    const uint4* qsrc = reinterpret_cast<const uint4*>(qb + base + (size_t)(q0 + w * 32 + ln) * DHEAD);
#pragma unroll
    for (int ds = 0; ds < 4; ++ds) {
      uint4 tq = qsrc[ds * 2 + hi];
      qf[ds] = *reinterpret_cast<short8*>(&tq);
    }
  }

  f32x16 o0, o1;
#pragma unroll
  for (int r = 0; r < 16; ++r) { o0[r] = 0.f; o1[r] = 0.f; }
  float m_run = -3.0e38f, l_run = 0.f;

  // staging roles
  const int sr = t >> 2;        // K row 0..63
  const int sc = (t & 3) * 2;   // K chunk base 0,2,4,6
  const int vp = t & 31;        // V row-pair 0..31
  const int vg = t >> 5;        // V d-group 0..7

  const uint4* kg = reinterpret_cast<const uint4*>(kb + base);
  const uint4* vgp = reinterpret_cast<const uint4*>(vb + base);

  uint4 kA = kg[(size_t)sr * 8 + sc];
  uint4 kB = kg[(size_t)sr * 8 + sc + 1];
  uint4 vA = vgp[(size_t)(vp * 2) * 8 + vg];
  uint4 vB = vgp[(size_t)(vp * 2 + 1) * 8 + vg];

  for (int kt = 0; kt < SEQ / 64; ++kt) {
    __syncthreads();  // prior tile's LDS reads done
    Ksm[sr * 8 + (sc ^ (sr & 7))] = kA;
    Ksm[sr * 8 + ((sc + 1) ^ (sr & 7))] = kB;
    {
      u16x8 a = *reinterpret_cast<u16x8*>(&vA);
      u16x8 b = *reinterpret_cast<u16x8*>(&vB);
#pragma unroll
      for (int j = 0; j < 8; ++j) {
        uint_t pw = (uint_t)a[j] | ((uint_t)b[j] << 16);
        int d = vg * 8 + j;  // d&7 == j
        Vtsm[d * 32 + (((vp >> 2) ^ j) << 2) + (vp & 3)] = pw;
      }
    }
    __syncthreads();  // staging visible

    if (kt + 1 < SEQ / 64) {  // prefetch next tile (hides under compute)
      size_t rb = (size_t)((kt + 1) * 64);
      kA = kg[(rb + sr) * 8 + sc];
      kB = kg[(rb + sr) * 8 + sc + 1];
      vA = vgp[(rb + vp * 2) * 8 + vg];
      vB = vgp[(rb + vp * 2 + 1) * 8 + vg];
    }

    // ---- S^T = K @ Q^T : lane = query ln, rows = keys ----
    f32x16 s0, s1;
#pragma unroll
    for (int r = 0; r < 16; ++r) { s0[r] = 0.f; s1[r] = 0.f; }
#pragma unroll
    for (int ds = 0; ds < 4; ++ds) {
      int ch = ds * 2 + hi;
      uint4 ta = Ksm[ln * 8 + (ch ^ (ln & 7))];
      s0 = mfma32(*reinterpret_cast<short8*>(&ta), qf[ds], s0);
      int r1 = 32 + ln;
      uint4 tb = Ksm[r1 * 8 + (ch ^ (r1 & 7))];
      s1 = mfma32(*reinterpret_cast<short8*>(&tb), qf[ds], s1);
    }

    // ---- online softmax (per lane = one query; partner lane l^32 holds other keys) ----
    float u[32];
#pragma unroll
    for (int r = 0; r < 16; ++r) { u[r] = s0[r]; u[16 + r] = s1[r]; }
    float mx = u[0];
#pragma unroll
    for (int r = 1; r < 32; ++r) mx = fmaxf(mx, u[r]);
    mx *= 0.125f;
    mx = fmaxf(mx, __shfl_xor(mx, 32, 64));
    float mnew = fmaxf(m_run, mx);
    float corr = __expf(m_run - mnew);
    m_run = mnew;
    float p[32];
    float rs = 0.f;
#pragma unroll
    for (int r = 0; r < 32; ++r) {
      p[r] = __expf(fmaf(u[r], 0.125f, -mnew));
      rs += p[r];
    }
    rs += __shfl_xor(rs, 32, 64);
    l_run = fmaf(l_run, corr, rs);
    o0 *= corr;
    o1 *= corr;

    // ---- P -> bf16 A/B fragment via cvt_pk + permlane32_swap (T12) ----
    short8 pa[4];
#pragma unroll
    for (int ks = 0; ks < 4; ++ks) {
      int g = ks * 8;
      uint_t w0 = cvtpk_bf16(p[g + 0], p[g + 1]);
      uint_t w1 = cvtpk_bf16(p[g + 2], p[g + 3]);
      uint_t w2 = cvtpk_bf16(p[g + 4], p[g + 5]);
      uint_t w3 = cvtpk_bf16(p[g + 6], p[g + 7]);
      asm volatile("v_permlane32_swap_b32 %0, %1" : "+v"(w0), "+v"(w2));
      asm volatile("v_permlane32_swap_b32 %0, %1" : "+v"(w1), "+v"(w3));
      uint_t tw[4] = {w0, w1, w2, w3};
      pa[ks] = *reinterpret_cast<short8*>(tw);
    }

    // ---- O^T += Vt @ P^T ----
#pragma unroll
    for (int ks = 0; ks < 4; ++ks) {
      int ch = ks * 2 + hi;
      uint4 ta = *reinterpret_cast<uint4*>(&Vtsm[ln * 32 + ((ch ^ (ln & 7)) << 2)]);
      o0 = mfma32(*reinterpret_cast<short8*>(&ta), pa[ks], o0);
      int d1 = 32 + ln;
      uint4 tb = *reinterpret_cast<uint4*>(&Vtsm[d1 * 32 + ((ch ^ (d1 & 7)) << 2)]);
      o1 = mfma32(*reinterpret_cast<short8*>(&tb), pa[ks], o1);
    }
  }

  // ---- epilogue: /l, * sigmoid gate, store [b, n, h*64+d] ----
  int n_i = q0 + w * 32 + ln;
  int rowg = b_i * SEQ + n_i;
  float gate = mg[(size_t)rowg * 32 + HEADS + h];
  float f = gate / l_run;
  float* dst = attn_out + (size_t)rowg * DIMM + h * DHEAD;
#pragma unroll
  for (int g = 0; g < 4; ++g) {
    float4 v0 = make_float4(o0[4 * g] * f, o0[4 * g + 1] * f, o0[4 * g + 2] * f, o0[4 * g + 3] * f);
    *reinterpret_cast<float4*>(dst + g * 8 + hi * 4) = v0;
    float4 v1 = make_float4(o1[4 * g] * f, o1[4 * g + 1] * f, o1[4 * g + 2] * f, o1[4 * g + 3] * f);
    *reinterpret_cast<float4*>(dst + 32 + g * 8 + hi * 4) = v1;
  }
}

// ---------------- launch ----------------
extern "C" void kernel_launch(void* const* d_in, const int* in_sizes, int n_in,
                              void* d_out, int out_size, void* d_ws, size_t ws_size,
                              hipStream_t stream) {
  const float* x       = (const float*)d_in[0];
  const float* vr      = (const float*)d_in[1];
  const float* gamma   = (const float*)d_in[2];
  const float* w_qkv   = (const float*)d_in[3];
  const float* w_mix   = (const float*)d_in[4];
  const float* b_mix   = (const float*)d_in[5];
  const float* w_gates = (const float*)d_in[6];
  const float* b_gates = (const float*)d_in[7];
  const float* w_out   = (const float*)d_in[8];

  float* out = (float*)d_out;
  float* orig_v = out + (size_t)MROWS * DIMM;   // second tuple output [b,h,n,d] fp32

  float* ws = (float*)d_ws;
  const size_t BUF = (size_t)MROWS * DIMM;      // 4,194,304 elements
  float* xn = ws;                               // fp32 [4096,1024]; reused as attn_out
  ushort_t* q_bf = (ushort_t*)(ws + BUF);       // bf16 [b,h,n,d]
  ushort_t* k_bf = q_bf + BUF;
  ushort_t* v_bf = k_bf + BUF;
  float* mg = (float*)(v_bf + BUF);             // [4096][32]: mix | gates
  float* attn_out = xn;

  k_rmsnorm<<<dim3(MROWS), dim3(256), 0, stream>>>(x, gamma, xn);
  k_mixgates<<<dim3(MROWS), dim3(128), 0, stream>>>(xn, w_mix, b_mix, w_gates, b_gates, mg);
  k_gemm<NQKV, 0><<<dim3(NQKV / 128, MROWS / 128), dim3(256), 0, stream>>>(
      xn, w_qkv, q_bf, k_bf, v_bf, orig_v, vr, mg, nullptr);
  k_attn<<<dim3(SEQ / 128, NB * HEADS), dim3(256), 0, stream>>>(q_bf, k_bf, v_bf, mg, attn_out);
  k_gemm<DIMM, 1><<<dim3(DIMM / 128, MROWS / 128), dim3(256), 0, stream>>>(
      attn_out, w_out, nullptr, nullptr, nullptr, nullptr, nullptr, nullptr, out);
}

// Round 5
// 359.269 us; speedup vs baseline: 5.3667x; 1.9725x over previous
//
#include <hip/hip_runtime.h>
#include <math.h>

#define HEADS 16
#define DHEAD 64
#define DIMM 1024
#define NQKV 3072
#define NB 2
#define SEQ 2048
#define MROWS 4096   // NB*SEQ

typedef unsigned short ushort_t;
typedef unsigned int uint_t;
typedef __attribute__((ext_vector_type(8))) short short8;
typedef __attribute__((ext_vector_type(8))) unsigned short u16x8;
typedef __attribute__((ext_vector_type(16))) float f32x16;

__device__ __forceinline__ ushort_t f2bf(float f) {
  uint_t u = __float_as_uint(f);
  u += 0x7fffu + ((u >> 16) & 1u);   // RNE
  return (ushort_t)(u >> 16);
}

__device__ __forceinline__ uint_t cvtpk_bf16(float lo, float hi) {
  uint_t r;
  asm("v_cvt_pk_bf16_f32 %0, %1, %2" : "=v"(r) : "v"(lo), "v"(hi));
  return r;
}

__device__ __forceinline__ f32x16 mfma32(short8 a, short8 b, f32x16 c) {
  return __builtin_amdgcn_mfma_f32_32x32x16_bf16(a, b, c, 0, 0, 0);
}

__device__ __forceinline__ void gload_lds16(const void* g, void* l) {
  __builtin_amdgcn_global_load_lds(
      (const __attribute__((address_space(1))) void*)g,
      (__attribute__((address_space(3))) void*)l, 16, 0, 0);
}

// ---------------- K1: RMSNorm -> xn fp32 (for mixgates) + xn bf16 (GEMM A) ----------------
__global__ __launch_bounds__(256) void k_rmsnorm(const float* __restrict__ x,
                                                 const float* __restrict__ gamma,
                                                 float* __restrict__ xn,
                                                 ushort_t* __restrict__ xn_bf) {
  int row = blockIdx.x;
  int t = threadIdx.x;
  float4 v = reinterpret_cast<const float4*>(x + (size_t)row * DIMM)[t];
  float ss = v.x * v.x + v.y * v.y + v.z * v.z + v.w * v.w;
#pragma unroll
  for (int o = 32; o >= 1; o >>= 1) ss += __shfl_xor(ss, o, 64);
  __shared__ float red[4];
  if ((t & 63) == 0) red[t >> 6] = ss;
  __syncthreads();
  ss = red[0] + red[1] + red[2] + red[3];
  float s = 32.0f / fmaxf(sqrtf(ss), 1e-12f);
  float4 g = reinterpret_cast<const float4*>(gamma)[t];
  float4 o4;
  o4.x = v.x * s * g.x;
  o4.y = v.y * s * g.y;
  o4.z = v.z * s * g.z;
  o4.w = v.w * s * g.w;
  reinterpret_cast<float4*>(xn + (size_t)row * DIMM)[t] = o4;
  ushort4 ob;
  ob.x = f2bf(o4.x); ob.y = f2bf(o4.y); ob.z = f2bf(o4.z); ob.w = f2bf(o4.w);
  *reinterpret_cast<ushort4*>(xn_bf + (size_t)row * DIMM + t * 4) = ob;
}

// ---------------- K1b: mix & gates projections + sigmoid ----------------
__global__ __launch_bounds__(128) void k_mixgates(const float* __restrict__ xn,
                                                  const float* __restrict__ w_mix,
                                                  const float* __restrict__ b_mix,
                                                  const float* __restrict__ w_gates,
                                                  const float* __restrict__ b_gates,
                                                  float* __restrict__ mg) {
  int row = blockIdx.x;
  int t = threadIdx.x;
  int out = t >> 2;   // 0..31
  int part = t & 3;   // 0..3 (256 K-elems each)
  const float* xr = xn + (size_t)row * DIMM;
  const float* w = (out < HEADS) ? (w_mix + out) : (w_gates + (out - HEADS));
  int k0 = part * 256;
  float acc = 0.f;
#pragma unroll 8
  for (int kk = 0; kk < 256; ++kk) acc += xr[k0 + kk] * w[(size_t)(k0 + kk) * HEADS];
  acc += __shfl_xor(acc, 1, 64);
  acc += __shfl_xor(acc, 2, 64);
  if (part == 0) {
    float bias = (out < HEADS) ? b_mix[out] : b_gates[out - HEADS];
    float val = acc + bias;
    mg[(size_t)row * 32 + out] = 1.f / (1.f + __expf(-val));
  }
}

// ---------------- transpose-convert: in [K][N] fp32 -> outT [N][K] bf16 ----------------
__global__ __launch_bounds__(256) void k_transpose_bf(const float* __restrict__ in,
                                                      ushort_t* __restrict__ outT,
                                                      int N, int K) {
  __shared__ float tile[32][33];
  int n0 = blockIdx.x * 32, k0 = blockIdx.y * 32;
  int t = threadIdx.x;
  int r = t >> 3, c4 = (t & 7) * 4;
  float4 v = *reinterpret_cast<const float4*>(in + (size_t)(k0 + r) * N + n0 + c4);
  tile[r][c4 + 0] = v.x; tile[r][c4 + 1] = v.y; tile[r][c4 + 2] = v.z; tile[r][c4 + 3] = v.w;
  __syncthreads();
  ushort4 o;
  o.x = f2bf(tile[c4 + 0][r]);
  o.y = f2bf(tile[c4 + 1][r]);
  o.z = f2bf(tile[c4 + 2][r]);
  o.w = f2bf(tile[c4 + 3][r]);
  *reinterpret_cast<ushort4*>(outT + (size_t)(n0 + r) * K + k0 + c4) = o;
}

// ---------------- bf16 MFMA GEMM: C[M,NCOLS] = A[M,1024] @ Bt[NCOLS,1024]^T ----------------
// 128x128 tile, BK=64, 256 threads = 4 waves (2x2), wave tile 64x64 = 2x2 mfma_32x32x16.
// LDS linear (global_load_lds dest), XOR swizzle applied on the GLOBAL source address
// (chunk ^ (row&7)) and on the ds_read side -> conflict-free b128 reads.
// MODE 0: QKV epilogue (q/k bf16, v lerped bf16, orig_v fp32 to d_out)
// MODE 1: plain fp32 store to outp [M,NCOLS]
template <int NCOLS, int MODE>
__global__ __launch_bounds__(256, 2) void k_gemm_bf(const ushort_t* __restrict__ A,
                                                    const ushort_t* __restrict__ Bt,
                                                    ushort_t* __restrict__ q_bf,
                                                    ushort_t* __restrict__ k_bf,
                                                    ushort_t* __restrict__ v_bf,
                                                    float* __restrict__ orig_v,
                                                    const float* __restrict__ vr,
                                                    const float* __restrict__ mg,
                                                    float* __restrict__ outp) {
  __shared__ __align__(16) ushort_t As[128 * 64];
  __shared__ __align__(16) ushort_t Bs[128 * 64];
  const int t = threadIdx.x;
  const int w = t >> 6;
  const int l = t & 63;
  const int ln = l & 31;
  const int hi = l >> 5;
  const int wm = w >> 1, wn = w & 1;
  const int m0 = blockIdx.y * 128, n0 = blockIdx.x * 128;

  f32x16 acc00, acc01, acc10, acc11;
#pragma unroll
  for (int r = 0; r < 16; ++r) { acc00[r] = 0.f; acc01[r] = 0.f; acc10[r] = 0.f; acc11[r] = 0.f; }

  const int srow8 = l >> 3;   // 0..7
  const int cp = l & 7;       // stored chunk position

  for (int k0 = 0; k0 < DIMM; k0 += 64) {
#pragma unroll
    for (int i = 0; i < 4; ++i) {
      int rowa = (i * 4 + w) * 8 + srow8;
      const ushort_t* ga = A + (size_t)(m0 + rowa) * DIMM + k0 + ((cp ^ (rowa & 7)) * 8);
      gload_lds16(ga, &As[(i * 4 + w) * 512]);
      const ushort_t* gb = Bt + (size_t)(n0 + rowa) * DIMM + k0 + ((cp ^ (rowa & 7)) * 8);
      gload_lds16(gb, &Bs[(i * 4 + w) * 512]);
    }
    __syncthreads();   // vmcnt(0) drain + visibility
#pragma unroll
    for (int ks = 0; ks < 4; ++ks) {
      int cl = ks * 2 + hi;
      int ra0 = wm * 64 + ln;
      int ra1 = wm * 64 + 32 + ln;
      int rb0 = wn * 64 + ln;
      int rb1 = wn * 64 + 32 + ln;
      short8 af0 = *reinterpret_cast<const short8*>(&As[ra0 * 64 + ((cl ^ (ra0 & 7)) * 8)]);
      short8 af1 = *reinterpret_cast<const short8*>(&As[ra1 * 64 + ((cl ^ (ra1 & 7)) * 8)]);
      short8 bf0 = *reinterpret_cast<const short8*>(&Bs[rb0 * 64 + ((cl ^ (rb0 & 7)) * 8)]);
      short8 bf1 = *reinterpret_cast<const short8*>(&Bs[rb1 * 64 + ((cl ^ (rb1 & 7)) * 8)]);
      acc00 = mfma32(af0, bf0, acc00);
      acc01 = mfma32(af0, bf1, acc01);
      acc10 = mfma32(af1, bf0, acc10);
      acc11 = mfma32(af1, bf1, acc11);
    }
    __syncthreads();   // compute done before next stage overwrites
  }

  // ---------------- epilogue ----------------
  auto do_tile = [&](const f32x16& a, int mt, int nt) {
    int nb = n0 + wn * 64 + nt * 32;       // wave-uniform base col
    if (MODE == 1) {
#pragma unroll
      for (int r = 0; r < 16; ++r) {
        int m_loc = wm * 64 + mt * 32 + (r & 3) + 8 * (r >> 2) + 4 * hi;
        int row = m0 + m_loc;
        outp[(size_t)row * NCOLS + nb + ln] = a[r];
      }
    } else {
      int part = nb >> 10;
      int hh = (nb & 1023) >> 6;
      int ddb = (nb & 63) + ln;
#pragma unroll
      for (int r = 0; r < 16; ++r) {
        int m_loc = wm * 64 + mt * 32 + (r & 3) + 8 * (r >> 2) + 4 * hi;
        int row = m0 + m_loc;
        int b_i = row >> 11, n_i = row & 2047;
        size_t idx = (((size_t)(b_i * HEADS + hh)) * SEQ + n_i) * DHEAD + ddb;
        float val = a[r];
        if (part == 0) {
          q_bf[idx] = f2bf(val);
        } else if (part == 1) {
          k_bf[idx] = f2bf(val);
        } else {
          orig_v[idx] = val;
          float mixv = mg[(size_t)row * 32 + hh];
          float fv = val + mixv * (vr[idx] - val);
          v_bf[idx] = f2bf(fv);
        }
      }
    }
  };
  do_tile(acc00, 0, 0);
  do_tile(acc01, 0, 1);
  do_tile(acc10, 1, 0);
  do_tile(acc11, 1, 1);
}

// ---------------- K3: bf16 MFMA flash attention + sigmoid gating ----------------
__global__ __launch_bounds__(256, 2) void k_attn(const ushort_t* __restrict__ qb,
                                                 const ushort_t* __restrict__ kb,
                                                 const ushort_t* __restrict__ vb,
                                                 const float* __restrict__ mg,
                                                 ushort_t* __restrict__ attn_bf) {
  __shared__ uint4 Ksm[64 * 8];     // [row][swz chunk]
  __shared__ uint_t Vtsm[64 * 32];  // [d][...] transposed V, pair-packed

  const int t = threadIdx.x;
  const int w = t >> 6;
  const int l = t & 63;
  const int hi = l >> 5;
  const int ln = l & 31;
  const int bh = blockIdx.y;
  const int q0 = blockIdx.x * 128;
  const int b_i = bh >> 4, h = bh & 15;

  const size_t base = (size_t)bh * SEQ * DHEAD;

  short8 qf[4];
  {
    const uint4* qsrc = reinterpret_cast<const uint4*>(qb + base + (size_t)(q0 + w * 32 + ln) * DHEAD);
#pragma unroll
    for (int ds = 0; ds < 4; ++ds) {
      uint4 tq = qsrc[ds * 2 + hi];
      qf[ds] = *reinterpret_cast<short8*>(&tq);
    }
  }

  f32x16 o0, o1;
#pragma unroll
  for (int r = 0; r < 16; ++r) { o0[r] = 0.f; o1[r] = 0.f; }
  float m_run = -3.0e38f, l_run = 0.f;

  const int sr = t >> 2;
  const int sc = (t & 3) * 2;
  const int vp = t & 31;
  const int vg = t >> 5;

  const uint4* kg = reinterpret_cast<const uint4*>(kb + base);
  const uint4* vgp = reinterpret_cast<const uint4*>(vb + base);

  uint4 kA = kg[(size_t)sr * 8 + sc];
  uint4 kB = kg[(size_t)sr * 8 + sc + 1];
  uint4 vA = vgp[(size_t)(vp * 2) * 8 + vg];
  uint4 vB = vgp[(size_t)(vp * 2 + 1) * 8 + vg];

  for (int kt = 0; kt < SEQ / 64; ++kt) {
    __syncthreads();
    Ksm[sr * 8 + (sc ^ (sr & 7))] = kA;
    Ksm[sr * 8 + ((sc + 1) ^ (sr & 7))] = kB;
    {
      u16x8 a = *reinterpret_cast<u16x8*>(&vA);
      u16x8 b = *reinterpret_cast<u16x8*>(&vB);
#pragma unroll
      for (int j = 0; j < 8; ++j) {
        uint_t pw = (uint_t)a[j] | ((uint_t)b[j] << 16);
        int d = vg * 8 + j;
        Vtsm[d * 32 + (((vp >> 2) ^ j) << 2) + (vp & 3)] = pw;
      }
    }
    __syncthreads();

    if (kt + 1 < SEQ / 64) {
      size_t rb = (size_t)((kt + 1) * 64);
      kA = kg[(rb + sr) * 8 + sc];
      kB = kg[(rb + sr) * 8 + sc + 1];
      vA = vgp[(rb + vp * 2) * 8 + vg];
      vB = vgp[(rb + vp * 2 + 1) * 8 + vg];
    }

    f32x16 s0, s1;
#pragma unroll
    for (int r = 0; r < 16; ++r) { s0[r] = 0.f; s1[r] = 0.f; }
#pragma unroll
    for (int ds = 0; ds < 4; ++ds) {
      int ch = ds * 2 + hi;
      uint4 ta = Ksm[ln * 8 + (ch ^ (ln & 7))];
      s0 = mfma32(*reinterpret_cast<short8*>(&ta), qf[ds], s0);
      int r1 = 32 + ln;
      uint4 tb = Ksm[r1 * 8 + (ch ^ (r1 & 7))];
      s1 = mfma32(*reinterpret_cast<short8*>(&tb), qf[ds], s1);
    }

    float u[32];
#pragma unroll
    for (int r = 0; r < 16; ++r) { u[r] = s0[r]; u[16 + r] = s1[r]; }
    float mx = u[0];
#pragma unroll
    for (int r = 1; r < 32; ++r) mx = fmaxf(mx, u[r]);
    mx *= 0.125f;
    mx = fmaxf(mx, __shfl_xor(mx, 32, 64));
    float mnew = fmaxf(m_run, mx);
    float corr = __expf(m_run - mnew);
    m_run = mnew;
    float p[32];
    float rs = 0.f;
#pragma unroll
    for (int r = 0; r < 32; ++r) {
      p[r] = __expf(fmaf(u[r], 0.125f, -mnew));
      rs += p[r];
    }
    rs += __shfl_xor(rs, 32, 64);
    l_run = fmaf(l_run, corr, rs);
    o0 *= corr;
    o1 *= corr;

    short8 pa[4];
#pragma unroll
    for (int ks = 0; ks < 4; ++ks) {
      int g = ks * 8;
      uint_t w0 = cvtpk_bf16(p[g + 0], p[g + 1]);
      uint_t w1 = cvtpk_bf16(p[g + 2], p[g + 3]);
      uint_t w2 = cvtpk_bf16(p[g + 4], p[g + 5]);
      uint_t w3 = cvtpk_bf16(p[g + 6], p[g + 7]);
      asm volatile("v_permlane32_swap_b32 %0, %1" : "+v"(w0), "+v"(w2));
      asm volatile("v_permlane32_swap_b32 %0, %1" : "+v"(w1), "+v"(w3));
      uint_t tw[4] = {w0, w1, w2, w3};
      pa[ks] = *reinterpret_cast<short8*>(tw);
    }

#pragma unroll
    for (int ks = 0; ks < 4; ++ks) {
      int ch = ks * 2 + hi;
      uint4 ta = *reinterpret_cast<uint4*>(&Vtsm[ln * 32 + ((ch ^ (ln & 7)) << 2)]);
      o0 = mfma32(*reinterpret_cast<short8*>(&ta), pa[ks], o0);
      int d1 = 32 + ln;
      uint4 tb = *reinterpret_cast<uint4*>(&Vtsm[d1 * 32 + ((ch ^ (d1 & 7)) << 2)]);
      o1 = mfma32(*reinterpret_cast<short8*>(&tb), pa[ks], o1);
    }
  }

  int n_i = q0 + w * 32 + ln;
  int rowg = b_i * SEQ + n_i;
  float gate = mg[(size_t)rowg * 32 + HEADS + h];
  float f = gate / l_run;
  ushort_t* dst = attn_bf + (size_t)rowg * DIMM + h * DHEAD;
#pragma unroll
  for (int g = 0; g < 4; ++g) {
    uint2 p0;
    p0.x = cvtpk_bf16(o0[4 * g] * f, o0[4 * g + 1] * f);
    p0.y = cvtpk_bf16(o0[4 * g + 2] * f, o0[4 * g + 3] * f);
    *reinterpret_cast<uint2*>(dst + g * 8 + hi * 4) = p0;
    uint2 p1;
    p1.x = cvtpk_bf16(o1[4 * g] * f, o1[4 * g + 1] * f);
    p1.y = cvtpk_bf16(o1[4 * g + 2] * f, o1[4 * g + 3] * f);
    *reinterpret_cast<uint2*>(dst + 32 + g * 8 + hi * 4) = p1;
  }
}

// ---------------- launch ----------------
extern "C" void kernel_launch(void* const* d_in, const int* in_sizes, int n_in,
                              void* d_out, int out_size, void* d_ws, size_t ws_size,
                              hipStream_t stream) {
  const float* x       = (const float*)d_in[0];
  const float* vr      = (const float*)d_in[1];
  const float* gamma   = (const float*)d_in[2];
  const float* w_qkv   = (const float*)d_in[3];
  const float* w_mix   = (const float*)d_in[4];
  const float* b_mix   = (const float*)d_in[5];
  const float* w_gates = (const float*)d_in[6];
  const float* b_gates = (const float*)d_in[7];
  const float* w_out   = (const float*)d_in[8];

  float* out = (float*)d_out;
  float* orig_v = out + (size_t)MROWS * DIMM;   // second tuple output [b,h,n,d] fp32

  const size_t BUF = (size_t)MROWS * DIMM;      // 4,194,304 elements
  char* wsb = (char*)d_ws;
  float*    xn      = (float*)wsb;                        wsb += BUF * 4;          // 16.78 MB
  ushort_t* xn_bf   = (ushort_t*)wsb;                     wsb += BUF * 2;          //  8.39 MB
  ushort_t* q_bf    = (ushort_t*)wsb;                     wsb += BUF * 2;
  ushort_t* k_bf    = (ushort_t*)wsb;                     wsb += BUF * 2;
  ushort_t* v_bf    = (ushort_t*)wsb;                     wsb += BUF * 2;
  ushort_t* attn_bf = (ushort_t*)wsb;                     wsb += BUF * 2;
  ushort_t* wqkv_t  = (ushort_t*)wsb;                     wsb += (size_t)NQKV * DIMM * 2;  // 6.29 MB
  ushort_t* wout_t  = (ushort_t*)wsb;                     wsb += (size_t)DIMM * DIMM * 2;  // 2.10 MB
  float*    mg      = (float*)wsb;                        wsb += (size_t)MROWS * 32 * 4;   // 0.52 MB

  k_transpose_bf<<<dim3(NQKV / 32, DIMM / 32), dim3(256), 0, stream>>>(w_qkv, wqkv_t, NQKV, DIMM);
  k_transpose_bf<<<dim3(DIMM / 32, DIMM / 32), dim3(256), 0, stream>>>(w_out, wout_t, DIMM, DIMM);
  k_rmsnorm<<<dim3(MROWS), dim3(256), 0, stream>>>(x, gamma, xn, xn_bf);
  k_mixgates<<<dim3(MROWS), dim3(128), 0, stream>>>(xn, w_mix, b_mix, w_gates, b_gates, mg);
  k_gemm_bf<NQKV, 0><<<dim3(NQKV / 128, MROWS / 128), dim3(256), 0, stream>>>(
      xn_bf, wqkv_t, q_bf, k_bf, v_bf, orig_v, vr, mg, nullptr);
  k_attn<<<dim3(SEQ / 128, NB * HEADS), dim3(256), 0, stream>>>(q_bf, k_bf, v_bf, mg, attn_bf);
  k_gemm_bf<DIMM, 1><<<dim3(DIMM / 128, MROWS / 128), dim3(256), 0, stream>>>(
      attn_bf, wout_t, nullptr, nullptr, nullptr, nullptr, nullptr, nullptr, out);
}

// Round 7
// 250.218 us; speedup vs baseline: 7.7056x; 1.4358x over previous
//
#include <hip/hip_runtime.h>
#include <math.h>

#define HEADS 16
#define DHEAD 64
#define DIMM 1024
#define NQKV 3072
#define NB 2
#define SEQ 2048
#define MROWS 4096   // NB*SEQ

typedef unsigned short ushort_t;
typedef unsigned int uint_t;
typedef __attribute__((ext_vector_type(8))) short short8;
typedef __attribute__((ext_vector_type(8))) unsigned short u16x8;
typedef __attribute__((ext_vector_type(16))) float f32x16;

__device__ __forceinline__ ushort_t f2bf(float f) {
  uint_t u = __float_as_uint(f);
  u += 0x7fffu + ((u >> 16) & 1u);   // RNE
  return (ushort_t)(u >> 16);
}

__device__ __forceinline__ uint_t cvtpk_bf16(float lo, float hi) {
  uint_t r;
  asm("v_cvt_pk_bf16_f32 %0, %1, %2" : "=v"(r) : "v"(lo), "v"(hi));
  return r;
}

__device__ __forceinline__ f32x16 mfma32(short8 a, short8 b, f32x16 c) {
  return __builtin_amdgcn_mfma_f32_32x32x16_bf16(a, b, c, 0, 0, 0);
}

__device__ __forceinline__ void gload_lds16(const void* g, void* l) {
  __builtin_amdgcn_global_load_lds(
      (const __attribute__((address_space(1))) void*)g,
      (__attribute__((address_space(3))) void*)l, 16, 0, 0);
}

// ---------------- K1: RMSNorm -> xn bf16 only ----------------
__global__ __launch_bounds__(256) void k_rmsnorm(const float* __restrict__ x,
                                                 const float* __restrict__ gamma,
                                                 ushort_t* __restrict__ xn_bf) {
  int row = blockIdx.x;
  int t = threadIdx.x;
  float4 v = reinterpret_cast<const float4*>(x + (size_t)row * DIMM)[t];
  float ss = v.x * v.x + v.y * v.y + v.z * v.z + v.w * v.w;
#pragma unroll
  for (int o = 32; o >= 1; o >>= 1) ss += __shfl_xor(ss, o, 64);
  __shared__ float red[4];
  if ((t & 63) == 0) red[t >> 6] = ss;
  __syncthreads();
  ss = red[0] + red[1] + red[2] + red[3];
  float s = 32.0f / fmaxf(sqrtf(ss), 1e-12f);
  float4 g = reinterpret_cast<const float4*>(gamma)[t];
  ushort4 ob;
  ob.x = f2bf(v.x * s * g.x);
  ob.y = f2bf(v.y * s * g.y);
  ob.z = f2bf(v.z * s * g.z);
  ob.w = f2bf(v.w * s * g.w);
  *reinterpret_cast<ushort4*>(xn_bf + (size_t)row * DIMM + t * 4) = ob;
}

// ---------------- pack w_mix|w_gates -> wt[32][1024] bf16 (transposed) ----------------
__global__ __launch_bounds__(256) void k_pack_w(const float* __restrict__ w_mix,
                                                const float* __restrict__ w_gates,
                                                ushort_t* __restrict__ wt) {
  int o = blockIdx.x;   // 0..31
  const float* w = (o < HEADS) ? (w_mix + o) : (w_gates + (o - HEADS));
  for (int k = threadIdx.x; k < DIMM; k += 256)
    wt[(size_t)o * DIMM + k] = f2bf(w[(size_t)k * HEADS]);
}

// ---------------- mixgates via MFMA: mg[row][0..31] = sigmoid(xn @ [w_mix|w_gates] + b) ----------------
// One wave per 32 rows. D[m][n] = xn_row_m . wt_row_n ; C-layout col=lane&31, row=(r&3)+8*(r>>2)+4*hi.
__global__ __launch_bounds__(64) void k_mixgates_mfma(const ushort_t* __restrict__ xn_bf,
                                                      const ushort_t* __restrict__ wt,
                                                      const float* __restrict__ b_mix,
                                                      const float* __restrict__ b_gates,
                                                      float* __restrict__ mg) {
  const int l = threadIdx.x;
  const int ln = l & 31;
  const int hi = l >> 5;
  const int m0 = blockIdx.x * 32;
  const uint4* arow = reinterpret_cast<const uint4*>(xn_bf + (size_t)(m0 + ln) * DIMM);
  const uint4* brow = reinterpret_cast<const uint4*>(wt + (size_t)ln * DIMM);
  f32x16 acc;
#pragma unroll
  for (int r = 0; r < 16; ++r) acc[r] = 0.f;
#pragma unroll 8
  for (int ks = 0; ks < 64; ++ks) {
    uint4 ta = arow[ks * 2 + hi];
    uint4 tb = brow[ks * 2 + hi];
    acc = mfma32(*reinterpret_cast<short8*>(&ta), *reinterpret_cast<short8*>(&tb), acc);
  }
  float bias = (ln < HEADS) ? b_mix[ln] : b_gates[ln - HEADS];
#pragma unroll
  for (int r = 0; r < 16; ++r) {
    int row = m0 + (r & 3) + 8 * (r >> 2) + 4 * hi;
    float val = acc[r] + bias;
    mg[(size_t)row * 32 + ln] = 1.f / (1.f + __expf(-val));
  }
}

// ---------------- transpose-convert: in [K][N] fp32 -> outT [N][K] bf16 ----------------
__global__ __launch_bounds__(256) void k_transpose_bf(const float* __restrict__ in,
                                                      ushort_t* __restrict__ outT,
                                                      int N, int K) {
  __shared__ float tile[32][33];
  int n0 = blockIdx.x * 32, k0 = blockIdx.y * 32;
  int t = threadIdx.x;
  int r = t >> 3, c4 = (t & 7) * 4;
  float4 v = *reinterpret_cast<const float4*>(in + (size_t)(k0 + r) * N + n0 + c4);
  tile[r][c4 + 0] = v.x; tile[r][c4 + 1] = v.y; tile[r][c4 + 2] = v.z; tile[r][c4 + 3] = v.w;
  __syncthreads();
  ushort4 o;
  o.x = f2bf(tile[c4 + 0][r]);
  o.y = f2bf(tile[c4 + 1][r]);
  o.z = f2bf(tile[c4 + 2][r]);
  o.w = f2bf(tile[c4 + 3][r]);
  *reinterpret_cast<ushort4*>(outT + (size_t)(n0 + r) * K + k0 + c4) = o;
}

// ---------------- bf16 MFMA GEMM: C[M,NCOLS] = A[M,1024] @ Bt[NCOLS,1024]^T ----------------
// 128x128 tile, BK=64, 256 threads = 4 waves (2x2), wave tile 64x64 = 2x2 mfma_32x32x16.
// MODE 0: QKV epilogue (q/k bf16, v lerped bf16, orig_v fp32 to d_out)
// MODE 1: plain fp32 store to outp [M,NCOLS]
template <int NCOLS, int MODE>
__global__ __launch_bounds__(256, 2) void k_gemm_bf(const ushort_t* __restrict__ A,
                                                    const ushort_t* __restrict__ Bt,
                                                    ushort_t* __restrict__ q_bf,
                                                    ushort_t* __restrict__ k_bf,
                                                    ushort_t* __restrict__ v_bf,
                                                    float* __restrict__ orig_v,
                                                    const float* __restrict__ vr,
                                                    const float* __restrict__ mg,
                                                    float* __restrict__ outp) {
  __shared__ __align__(16) ushort_t As[128 * 64];
  __shared__ __align__(16) ushort_t Bs[128 * 64];
  const int t = threadIdx.x;
  const int w = t >> 6;
  const int l = t & 63;
  const int ln = l & 31;
  const int hi = l >> 5;
  const int wm = w >> 1, wn = w & 1;
  const int m0 = blockIdx.y * 128, n0 = blockIdx.x * 128;

  f32x16 acc00, acc01, acc10, acc11;
#pragma unroll
  for (int r = 0; r < 16; ++r) { acc00[r] = 0.f; acc01[r] = 0.f; acc10[r] = 0.f; acc11[r] = 0.f; }

  const int srow8 = l >> 3;   // 0..7
  const int cp = l & 7;       // stored chunk position

  for (int k0 = 0; k0 < DIMM; k0 += 64) {
#pragma unroll
    for (int i = 0; i < 4; ++i) {
      int rowa = (i * 4 + w) * 8 + srow8;
      const ushort_t* ga = A + (size_t)(m0 + rowa) * DIMM + k0 + ((cp ^ (rowa & 7)) * 8);
      gload_lds16(ga, &As[(i * 4 + w) * 512]);
      const ushort_t* gb = Bt + (size_t)(n0 + rowa) * DIMM + k0 + ((cp ^ (rowa & 7)) * 8);
      gload_lds16(gb, &Bs[(i * 4 + w) * 512]);
    }
    __syncthreads();   // vmcnt(0) drain + visibility
#pragma unroll
    for (int ks = 0; ks < 4; ++ks) {
      int cl = ks * 2 + hi;
      int ra0 = wm * 64 + ln;
      int ra1 = wm * 64 + 32 + ln;
      int rb0 = wn * 64 + ln;
      int rb1 = wn * 64 + 32 + ln;
      short8 af0 = *reinterpret_cast<const short8*>(&As[ra0 * 64 + ((cl ^ (ra0 & 7)) * 8)]);
      short8 af1 = *reinterpret_cast<const short8*>(&As[ra1 * 64 + ((cl ^ (ra1 & 7)) * 8)]);
      short8 bf0 = *reinterpret_cast<const short8*>(&Bs[rb0 * 64 + ((cl ^ (rb0 & 7)) * 8)]);
      short8 bf1 = *reinterpret_cast<const short8*>(&Bs[rb1 * 64 + ((cl ^ (rb1 & 7)) * 8)]);
      acc00 = mfma32(af0, bf0, acc00);
      acc01 = mfma32(af0, bf1, acc01);
      acc10 = mfma32(af1, bf0, acc10);
      acc11 = mfma32(af1, bf1, acc11);
    }
    __syncthreads();   // compute done before next stage overwrites
  }

  // ---------------- epilogue ----------------
  auto do_tile = [&](const f32x16& a, int mt, int nt) {
    int nb = n0 + wn * 64 + nt * 32;       // wave-uniform base col
    if (MODE == 1) {
#pragma unroll
      for (int r = 0; r < 16; ++r) {
        int m_loc = wm * 64 + mt * 32 + (r & 3) + 8 * (r >> 2) + 4 * hi;
        int row = m0 + m_loc;
        outp[(size_t)row * NCOLS + nb + ln] = a[r];
      }
    } else {
      int part = nb >> 10;
      int hh = (nb & 1023) >> 6;
      int ddb = (nb & 63) + ln;
#pragma unroll
      for (int r = 0; r < 16; ++r) {
        int m_loc = wm * 64 + mt * 32 + (r & 3) + 8 * (r >> 2) + 4 * hi;
        int row = m0 + m_loc;
        int b_i = row >> 11, n_i = row & 2047;
        size_t idx = (((size_t)(b_i * HEADS + hh)) * SEQ + n_i) * DHEAD + ddb;
        float val = a[r];
        if (part == 0) {
          q_bf[idx] = f2bf(val);
        } else if (part == 1) {
          k_bf[idx] = f2bf(val);
        } else {
          orig_v[idx] = val;
          float mixv = mg[(size_t)row * 32 + hh];
          float fv = val + mixv * (vr[idx] - val);
          v_bf[idx] = f2bf(fv);
        }
      }
    }
  };
  do_tile(acc00, 0, 0);
  do_tile(acc01, 0, 1);
  do_tile(acc10, 1, 0);
  do_tile(acc11, 1, 1);
}

// ---------------- K3: bf16 MFMA flash attention + sigmoid gating ----------------
__global__ __launch_bounds__(256, 2) void k_attn(const ushort_t* __restrict__ qb,
                                                 const ushort_t* __restrict__ kb,
                                                 const ushort_t* __restrict__ vb,
                                                 const float* __restrict__ mg,
                                                 ushort_t* __restrict__ attn_bf) {
  __shared__ uint4 Ksm[64 * 8];     // [row][swz chunk]
  __shared__ uint_t Vtsm[64 * 32];  // [d][...] transposed V, pair-packed

  const int t = threadIdx.x;
  const int w = t >> 6;
  const int l = t & 63;
  const int hi = l >> 5;
  const int ln = l & 31;
  const int bh = blockIdx.y;
  const int q0 = blockIdx.x * 128;
  const int b_i = bh >> 4, h = bh & 15;

  const size_t base = (size_t)bh * SEQ * DHEAD;

  short8 qf[4];
  {
    const uint4* qsrc = reinterpret_cast<const uint4*>(qb + base + (size_t)(q0 + w * 32 + ln) * DHEAD);
#pragma unroll
    for (int ds = 0; ds < 4; ++ds) {
      uint4 tq = qsrc[ds * 2 + hi];
      qf[ds] = *reinterpret_cast<short8*>(&tq);
    }
  }

  f32x16 o0, o1;
#pragma unroll
  for (int r = 0; r < 16; ++r) { o0[r] = 0.f; o1[r] = 0.f; }
  float m_run = -3.0e38f, l_run = 0.f;

  const int sr = t >> 2;
  const int sc = (t & 3) * 2;
  const int vp = t & 31;
  const int vg = t >> 5;

  const uint4* kg = reinterpret_cast<const uint4*>(kb + base);
  const uint4* vgp = reinterpret_cast<const uint4*>(vb + base);

  uint4 kA = kg[(size_t)sr * 8 + sc];
  uint4 kB = kg[(size_t)sr * 8 + sc + 1];
  uint4 vA = vgp[(size_t)(vp * 2) * 8 + vg];
  uint4 vB = vgp[(size_t)(vp * 2 + 1) * 8 + vg];

  for (int kt = 0; kt < SEQ / 64; ++kt) {
    __syncthreads();
    Ksm[sr * 8 + (sc ^ (sr & 7))] = kA;
    Ksm[sr * 8 + ((sc + 1) ^ (sr & 7))] = kB;
    {
      u16x8 a = *reinterpret_cast<u16x8*>(&vA);
      u16x8 b = *reinterpret_cast<u16x8*>(&vB);
#pragma unroll
      for (int j = 0; j < 8; ++j) {
        uint_t pw = (uint_t)a[j] | ((uint_t)b[j] << 16);
        int d = vg * 8 + j;
        Vtsm[d * 32 + (((vp >> 2) ^ j) << 2) + (vp & 3)] = pw;
      }
    }
    __syncthreads();

    if (kt + 1 < SEQ / 64) {
      size_t rb = (size_t)((kt + 1) * 64);
      kA = kg[(rb + sr) * 8 + sc];
      kB = kg[(rb + sr) * 8 + sc + 1];
      vA = vgp[(rb + vp * 2) * 8 + vg];
      vB = vgp[(rb + vp * 2 + 1) * 8 + vg];
    }

    f32x16 s0, s1;
#pragma unroll
    for (int r = 0; r < 16; ++r) { s0[r] = 0.f; s1[r] = 0.f; }
#pragma unroll
    for (int ds = 0; ds < 4; ++ds) {
      int ch = ds * 2 + hi;
      uint4 ta = Ksm[ln * 8 + (ch ^ (ln & 7))];
      s0 = mfma32(*reinterpret_cast<short8*>(&ta), qf[ds], s0);
      int r1 = 32 + ln;
      uint4 tb = Ksm[r1 * 8 + (ch ^ (r1 & 7))];
      s1 = mfma32(*reinterpret_cast<short8*>(&tb), qf[ds], s1);
    }

    float u[32];
#pragma unroll
    for (int r = 0; r < 16; ++r) { u[r] = s0[r]; u[16 + r] = s1[r]; }
    float mx = u[0];
#pragma unroll
    for (int r = 1; r < 32; ++r) mx = fmaxf(mx, u[r]);
    mx *= 0.125f;
    mx = fmaxf(mx, __shfl_xor(mx, 32, 64));
    float mnew = fmaxf(m_run, mx);
    float corr = __expf(m_run - mnew);
    m_run = mnew;
    float p[32];
    float rs = 0.f;
#pragma unroll
    for (int r = 0; r < 32; ++r) {
      p[r] = __expf(fmaf(u[r], 0.125f, -mnew));
      rs += p[r];
    }
    rs += __shfl_xor(rs, 32, 64);
    l_run = fmaf(l_run, corr, rs);
    o0 *= corr;
    o1 *= corr;

    short8 pa[4];
#pragma unroll
    for (int ks = 0; ks < 4; ++ks) {
      int g = ks * 8;
      uint_t w0 = cvtpk_bf16(p[g + 0], p[g + 1]);
      uint_t w1 = cvtpk_bf16(p[g + 2], p[g + 3]);
      uint_t w2 = cvtpk_bf16(p[g + 4], p[g + 5]);
      uint_t w3 = cvtpk_bf16(p[g + 6], p[g + 7]);
      asm volatile("v_permlane32_swap_b32 %0, %1" : "+v"(w0), "+v"(w2));
      asm volatile("v_permlane32_swap_b32 %0, %1" : "+v"(w1), "+v"(w3));
      uint_t tw[4] = {w0, w1, w2, w3};
      pa[ks] = *reinterpret_cast<short8*>(tw);
    }

#pragma unroll
    for (int ks = 0; ks < 4; ++ks) {
      int ch = ks * 2 + hi;
      uint4 ta = *reinterpret_cast<uint4*>(&Vtsm[ln * 32 + ((ch ^ (ln & 7)) << 2)]);
      o0 = mfma32(*reinterpret_cast<short8*>(&ta), pa[ks], o0);
      int d1 = 32 + ln;
      uint4 tb = *reinterpret_cast<uint4*>(&Vtsm[d1 * 32 + ((ch ^ (d1 & 7)) << 2)]);
      o1 = mfma32(*reinterpret_cast<short8*>(&tb), pa[ks], o1);
    }
  }

  int n_i = q0 + w * 32 + ln;
  int rowg = b_i * SEQ + n_i;
  float gate = mg[(size_t)rowg * 32 + HEADS + h];
  float f = gate / l_run;
  ushort_t* dst = attn_bf + (size_t)rowg * DIMM + h * DHEAD;
#pragma unroll
  for (int g = 0; g < 4; ++g) {
    uint2 p0;
    p0.x = cvtpk_bf16(o0[4 * g] * f, o0[4 * g + 1] * f);
    p0.y = cvtpk_bf16(o0[4 * g + 2] * f, o0[4 * g + 3] * f);
    *reinterpret_cast<uint2*>(dst + g * 8 + hi * 4) = p0;
    uint2 p1;
    p1.x = cvtpk_bf16(o1[4 * g] * f, o1[4 * g + 1] * f);
    p1.y = cvtpk_bf16(o1[4 * g + 2] * f, o1[4 * g + 3] * f);
    *reinterpret_cast<uint2*>(dst + 32 + g * 8 + hi * 4) = p1;
  }
}

// ---------------- launch ----------------
extern "C" void kernel_launch(void* const* d_in, const int* in_sizes, int n_in,
                              void* d_out, int out_size, void* d_ws, size_t ws_size,
                              hipStream_t stream) {
  const float* x       = (const float*)d_in[0];
  const float* vr      = (const float*)d_in[1];
  const float* gamma   = (const float*)d_in[2];
  const float* w_qkv   = (const float*)d_in[3];
  const float* w_mix   = (const float*)d_in[4];
  const float* b_mix   = (const float*)d_in[5];
  const float* w_gates = (const float*)d_in[6];
  const float* b_gates = (const float*)d_in[7];
  const float* w_out   = (const float*)d_in[8];

  float* out = (float*)d_out;
  float* orig_v = out + (size_t)MROWS * DIMM;   // second tuple output [b,h,n,d] fp32

  const size_t BUF = (size_t)MROWS * DIMM;      // 4,194,304 elements
  char* wsb = (char*)d_ws;
  ushort_t* xn_bf   = (ushort_t*)wsb;                     wsb += BUF * 2;          // 8.39 MB
  ushort_t* q_bf    = (ushort_t*)wsb;                     wsb += BUF * 2;
  ushort_t* k_bf    = (ushort_t*)wsb;                     wsb += BUF * 2;
  ushort_t* v_bf    = (ushort_t*)wsb;                     wsb += BUF * 2;
  ushort_t* attn_bf = (ushort_t*)wsb;                     wsb += BUF * 2;
  ushort_t* wqkv_t  = (ushort_t*)wsb;                     wsb += (size_t)NQKV * DIMM * 2;  // 6.29 MB
  ushort_t* wout_t  = (ushort_t*)wsb;                     wsb += (size_t)DIMM * DIMM * 2;  // 2.10 MB
  ushort_t* wt_mg   = (ushort_t*)wsb;                     wsb += (size_t)32 * DIMM * 2;    // 64 KB
  float*    mg      = (float*)wsb;                        wsb += (size_t)MROWS * 32 * 4;   // 0.52 MB

  k_pack_w<<<dim3(32), dim3(256), 0, stream>>>(w_mix, w_gates, wt_mg);
  k_transpose_bf<<<dim3(NQKV / 32, DIMM / 32), dim3(256), 0, stream>>>(w_qkv, wqkv_t, NQKV, DIMM);
  k_transpose_bf<<<dim3(DIMM / 32, DIMM / 32), dim3(256), 0, stream>>>(w_out, wout_t, DIMM, DIMM);
  k_rmsnorm<<<dim3(MROWS), dim3(256), 0, stream>>>(x, gamma, xn_bf);
  k_mixgates_mfma<<<dim3(MROWS / 32), dim3(64), 0, stream>>>(xn_bf, wt_mg, b_mix, b_gates, mg);
  k_gemm_bf<NQKV, 0><<<dim3(NQKV / 128, MROWS / 128), dim3(256), 0, stream>>>(
      xn_bf, wqkv_t, q_bf, k_bf, v_bf, orig_v, vr, mg, nullptr);
  k_attn<<<dim3(SEQ / 128, NB * HEADS), dim3(256), 0, stream>>>(q_bf, k_bf, v_bf, mg, attn_bf);
  k_gemm_bf<DIMM, 1><<<dim3(DIMM / 128, MROWS / 128), dim3(256), 0, stream>>>(
      attn_bf, wout_t, nullptr, nullptr, nullptr, nullptr, nullptr, nullptr, out);
}